// Round 1
// baseline (186.303 us; speedup 1.0000x reference)
//
#include <hip/hip_runtime.h>

// out[i,j] = eps[i]*eps_perm[i]*rho/(2*pi*sigma) * exp(-||nuc_i - sb_j||^2/(2*sigma))
//          + eps[i]*d_drop[i]*chi_ambient[j]
// N = 8192 rows (CBs), M = 4096 cols (SBs). f32 in (insertion order), f32 out.
//
// R5 PASSED (dur_us 175). R6 PASSED (dur_us 158.7): 4 rows/block + NT float4
// stores. rocprof top-5 = harness 512 MiB d_ws poisons (85-87 us @ ~6.2 TB/s);
// our kernel < 84.7 us, floor = 134 MB / 6.3 TB/s ~= 21 us.
//
// R7 = MEASUREMENT ROUND (no algorithmic change): dur_us cannot separate
// "kernel at 21 us floor" from "kernel at 45+ us" because harness re-poison
// (~130-140 us, fixed) dominates and the kernel never appears in top-5.
// We launch an IDENTICAL probe pass writing into d_ws (harness-poisoned
// workspace, zero correctness risk) before the real pass:
//     dur_new - 158.7 = t_kernel  (exact, same code/grid/store path)
// If dur_new ~= 180 -> kernel is at the write roofline -> remove probe and
// declare ROOFLINE. If dur_new >= ~195 -> >=1.8x headroom in the store path
// -> next round A/Bs NT vs cached stores with this same probe mechanism.

typedef float float4v __attribute__((ext_vector_type(4)));

#define ROWS 4

__global__ __launch_bounds__(256) void rate_kernel(
    const float* __restrict__ nuc,          // [N,2]
    const float* __restrict__ sb,           // [M,2]
    const float* __restrict__ epsilon_perm, // [N]
    const float* __restrict__ epsilon,      // [N]
    const float* __restrict__ d_drop,       // [N]
    const float* __restrict__ rho_SB,       // [1]
    const float* __restrict__ sigma_SB,     // [1]
    const float* __restrict__ chi,          // [M]
    float* __restrict__ out,                // [N,M] f32
    int M)
{
    const int r0  = blockIdx.x * ROWS;
    const int tid = threadIdx.x;

    const float rho = rho_SB[0];
    const float sig = sigma_SB[0];
    // exp(-d2/(2s)) = exp2(d2 * (-1/(2s)) * log2(e))
    const float scale = (-0.5f / sig) * 1.4426950408889634f;
    const float cnorm = 0.15915494309189535f / sig;   // 1/(2*pi*sigma)

    // per-row scalars: block-uniform -> SGPRs
    float nx[ROWS], ny[ROWS], coef[ROWS], lamc[ROWS];
#pragma unroll
    for (int r = 0; r < ROWS; ++r) {
        const float2 nxy = ((const float2*)nuc)[r0 + r];
        nx[r] = nxy.x;
        ny[r] = nxy.y;
        const float e = epsilon[r0 + r];
        coef[r] = e * epsilon_perm[r0 + r] * rho * cnorm;
        lamc[r] = e * d_drop[r0 + r];
    }

    const float4* sb4  = (const float4*)sb;   // 2 (x,y) pairs per float4
    const float4* chi4 = (const float4*)chi;

    for (int j0 = tid * 4; j0 < M; j0 += 256 * 4) {
        const float4 s0 = sb4[j0 / 2];
        const float4 s1 = sb4[j0 / 2 + 1];
        const float4 cv = chi4[j0 / 4];
        const float sx[4] = { s0.x, s0.z, s1.x, s1.z };
        const float sy[4] = { s0.y, s0.w, s1.y, s1.w };
        const float ch[4] = { cv.x, cv.y, cv.z, cv.w };

#pragma unroll
        for (int r = 0; r < ROWS; ++r) {
            float4v res;
#pragma unroll
            for (int k = 0; k < 4; ++k) {
                const float dx = nx[r] - sx[k];
                const float dy = ny[r] - sy[k];
                const float d2 = fmaf(dx, dx, dy * dy);
                const float ev = exp2f(d2 * scale);
                res[k] = fmaf(coef[r], ev, lamc[r] * ch[k]);
            }
            __builtin_nontemporal_store(
                res, (float4v*)(out + (size_t)(r0 + r) * (size_t)M + j0));
        }
    }
}

// tail kernel (1 row/block) — only launched if N % ROWS != 0 (not the case
// for N=8192, kept for robustness)
__global__ __launch_bounds__(256) void rate_kernel_1(
    const float* __restrict__ nuc, const float* __restrict__ sb,
    const float* __restrict__ epsilon_perm, const float* __restrict__ epsilon,
    const float* __restrict__ d_drop, const float* __restrict__ rho_SB,
    const float* __restrict__ sigma_SB, const float* __restrict__ chi,
    float* __restrict__ out, int M, int row0)
{
    const int row = row0 + blockIdx.x;
    const int tid = threadIdx.x;
    const float2 nxy = ((const float2*)nuc)[row];
    const float e   = epsilon[row];
    const float sig = sigma_SB[0];
    const float scale = (-0.5f / sig) * 1.4426950408889634f;
    const float coef = e * epsilon_perm[row] * rho_SB[0] * (0.15915494309189535f / sig);
    const float lamc = e * d_drop[row];
    float* orow = out + (size_t)row * (size_t)M;
    for (int j = tid; j < M; j += 256) {
        const float dx = nxy.x - sb[2 * j];
        const float dy = nxy.y - sb[2 * j + 1];
        const float ev = exp2f(fmaf(dx, dx, dy * dy) * scale);
        orow[j] = fmaf(coef, ev, lamc * chi[j]);
    }
}

extern "C" void kernel_launch(void* const* d_in, const int* in_sizes, int n_in,
                              void* d_out, int out_size, void* d_ws, size_t ws_size,
                              hipStream_t stream) {
    // INSERTION (setup_inputs dict) order.
    const float* nuc = (const float*)d_in[0]; // nuc_locations [N,2]
    const float* sb  = (const float*)d_in[1]; // SB_locations [M,2]
    const float* epp = (const float*)d_in[2]; // epsilon_perm [N]
    const float* eps = (const float*)d_in[3]; // epsilon [N]
    const float* ddp = (const float*)d_in[4]; // d_drop [N]
    const float* rho = (const float*)d_in[5]; // rho_SB [1]
    const float* sig = (const float*)d_in[6]; // sigma_SB [1]
    const float* chi = (const float*)d_in[7]; // chi_ambient [M]
    float* out = (float*)d_out;

    const int M = in_sizes[7];   // 4096 (chi_ambient)
    const int N = out_size / M;  // 8192

    const int nb = N / ROWS;

    // R7 PROBE: identical pass into d_ws (512 MiB >= 134 MB out_size).
    // dur_us delta vs R6 (158.7) == standalone kernel duration.
    if (nb > 0 && ws_size >= (size_t)out_size) {
        float* probe = (float*)d_ws;
        rate_kernel<<<nb, 256, 0, stream>>>(nuc, sb, epp, eps, ddp, rho, sig,
                                            chi, probe, M);
    }

    // Real pass (byte-identical to R6 output path).
    if (nb > 0)
        rate_kernel<<<nb, 256, 0, stream>>>(nuc, sb, epp, eps, ddp, rho, sig,
                                            chi, out, M);
    const int tail = N - nb * ROWS;
    if (tail > 0)
        rate_kernel_1<<<tail, 256, 0, stream>>>(nuc, sb, epp, eps, ddp, rho,
                                                sig, chi, out, M, nb * ROWS);
}

// Round 2
// 152.391 us; speedup vs baseline: 1.2225x; 1.2225x over previous
//
#include <hip/hip_runtime.h>

// out[i,j] = eps[i]*eps_perm[i]*rho/(2*pi*sigma) * exp(-||nuc_i - sb_j||^2/(2*sigma))
//          + eps[i]*d_drop[i]*chi_ambient[j]
// N = 8192 rows (CBs), M = 4096 cols (SBs). f32 in (insertion order), f32 out.
//
// Measurement ledger:
//   R6: dur 158.75 = fixed + t_kernel           (ROWS=4 + NT stores)
//   R7: dur 186.30 = fixed + 2*t_kernel         (probe pass into d_ws)
//   => t_kernel = 27.55 us, fixed harness = 131.2 us (consistent to 0.1 us).
//   Kernel store BW = 134 MB / 27.55 us = 4.87 TB/s, vs 6.3-6.4 TB/s the
//   rocclr fill kernels sustain with PLAIN stores in the same graph.
//   => store path has ~22% headroom; compute (~5 us VALU+trans) is hidden.
//
// R8: single-variable A/B — NT store -> plain vector store (probe removed).
//   dur = 131.2 + t_plain. Predict ~153 if NT was the cap; ~158.7 if neutral;
//   >=162 if write-allocate pollution makes plain worse (then revert + stop).

typedef float float4v __attribute__((ext_vector_type(4)));

#define ROWS 4

__global__ __launch_bounds__(256) void rate_kernel(
    const float* __restrict__ nuc,          // [N,2]
    const float* __restrict__ sb,           // [M,2]
    const float* __restrict__ epsilon_perm, // [N]
    const float* __restrict__ epsilon,      // [N]
    const float* __restrict__ d_drop,       // [N]
    const float* __restrict__ rho_SB,       // [1]
    const float* __restrict__ sigma_SB,     // [1]
    const float* __restrict__ chi,          // [M]
    float* __restrict__ out,                // [N,M] f32
    int M)
{
    const int r0  = blockIdx.x * ROWS;
    const int tid = threadIdx.x;

    const float rho = rho_SB[0];
    const float sig = sigma_SB[0];
    // exp(-d2/(2s)) = exp2(d2 * (-1/(2s)) * log2(e))
    const float scale = (-0.5f / sig) * 1.4426950408889634f;
    const float cnorm = 0.15915494309189535f / sig;   // 1/(2*pi*sigma)

    // per-row scalars: block-uniform -> SGPRs
    float nx[ROWS], ny[ROWS], coef[ROWS], lamc[ROWS];
#pragma unroll
    for (int r = 0; r < ROWS; ++r) {
        const float2 nxy = ((const float2*)nuc)[r0 + r];
        nx[r] = nxy.x;
        ny[r] = nxy.y;
        const float e = epsilon[r0 + r];
        coef[r] = e * epsilon_perm[r0 + r] * rho * cnorm;
        lamc[r] = e * d_drop[r0 + r];
    }

    const float4* sb4  = (const float4*)sb;   // 2 (x,y) pairs per float4
    const float4* chi4 = (const float4*)chi;

    for (int j0 = tid * 4; j0 < M; j0 += 256 * 4) {
        const float4 s0 = sb4[j0 / 2];
        const float4 s1 = sb4[j0 / 2 + 1];
        const float4 cv = chi4[j0 / 4];
        const float sx[4] = { s0.x, s0.z, s1.x, s1.z };
        const float sy[4] = { s0.y, s0.w, s1.y, s1.w };
        const float ch[4] = { cv.x, cv.y, cv.z, cv.w };

#pragma unroll
        for (int r = 0; r < ROWS; ++r) {
            float4v res;
#pragma unroll
            for (int k = 0; k < 4; ++k) {
                const float dx = nx[r] - sx[k];
                const float dy = ny[r] - sy[k];
                const float d2 = fmaf(dx, dx, dy * dy);
                const float ev = exp2f(d2 * scale);
                res[k] = fmaf(coef[r], ev, lamc[r] * ch[k]);
            }
            // R8: plain (cached) store — A/B vs R6/R7's nontemporal store.
            *(float4v*)(out + (size_t)(r0 + r) * (size_t)M + j0) = res;
        }
    }
}

// tail kernel (1 row/block) — only launched if N % ROWS != 0 (not the case
// for N=8192, kept for robustness)
__global__ __launch_bounds__(256) void rate_kernel_1(
    const float* __restrict__ nuc, const float* __restrict__ sb,
    const float* __restrict__ epsilon_perm, const float* __restrict__ epsilon,
    const float* __restrict__ d_drop, const float* __restrict__ rho_SB,
    const float* __restrict__ sigma_SB, const float* __restrict__ chi,
    float* __restrict__ out, int M, int row0)
{
    const int row = row0 + blockIdx.x;
    const int tid = threadIdx.x;
    const float2 nxy = ((const float2*)nuc)[row];
    const float e   = epsilon[row];
    const float sig = sigma_SB[0];
    const float scale = (-0.5f / sig) * 1.4426950408889634f;
    const float coef = e * epsilon_perm[row] * rho_SB[0] * (0.15915494309189535f / sig);
    const float lamc = e * d_drop[row];
    float* orow = out + (size_t)row * (size_t)M;
    for (int j = tid; j < M; j += 256) {
        const float dx = nxy.x - sb[2 * j];
        const float dy = nxy.y - sb[2 * j + 1];
        const float ev = exp2f(fmaf(dx, dx, dy * dy) * scale);
        orow[j] = fmaf(coef, ev, lamc * chi[j]);
    }
}

extern "C" void kernel_launch(void* const* d_in, const int* in_sizes, int n_in,
                              void* d_out, int out_size, void* d_ws, size_t ws_size,
                              hipStream_t stream) {
    // INSERTION (setup_inputs dict) order.
    const float* nuc = (const float*)d_in[0]; // nuc_locations [N,2]
    const float* sb  = (const float*)d_in[1]; // SB_locations [M,2]
    const float* epp = (const float*)d_in[2]; // epsilon_perm [N]
    const float* eps = (const float*)d_in[3]; // epsilon [N]
    const float* ddp = (const float*)d_in[4]; // d_drop [N]
    const float* rho = (const float*)d_in[5]; // rho_SB [1]
    const float* sig = (const float*)d_in[6]; // sigma_SB [1]
    const float* chi = (const float*)d_in[7]; // chi_ambient [M]
    float* out = (float*)d_out;

    const int M = in_sizes[7];   // 4096 (chi_ambient)
    const int N = out_size / M;  // 8192

    const int nb = N / ROWS;
    if (nb > 0)
        rate_kernel<<<nb, 256, 0, stream>>>(nuc, sb, epp, eps, ddp, rho, sig,
                                            chi, out, M);
    const int tail = N - nb * ROWS;
    if (tail > 0)
        rate_kernel_1<<<tail, 256, 0, stream>>>(nuc, sb, epp, eps, ddp, rho,
                                                sig, chi, out, M, nb * ROWS);
}